// Round 2
// baseline (7421.507 us; speedup 1.0000x reference)
//
#include <hip/hip_runtime.h>
#include <cstdint>
#include <cstddef>

#define EMB 256
#define NN 20000
#define NE 200000
#define NE2 400000

// ---------------------------------------------------------------------------
// Threefry2x32 (JAX default PRNG), 20 rounds. key = (0, 42) for jax.random.key(42).
// PARTITIONABLE mode (JAX >= 0.5 default): per-element 64-bit counter,
//   (o0,o1) = threefry(key, (count>>32, count&0xffffffff)); bits = o0 ^ o1.
// For e < 2^32: x0 = 0, x1 = e.
// ---------------------------------------------------------------------------
__device__ __forceinline__ unsigned rotl32(unsigned v, int d) {
    return (v << d) | (v >> (32 - d));
}

__device__ __forceinline__ void threefry2x32(unsigned k0, unsigned k1,
                                             unsigned x0, unsigned x1,
                                             unsigned& o0, unsigned& o1) {
    unsigned k2 = k0 ^ k1 ^ 0x1BD11BDAu;
    x0 += k0; x1 += k1;
#define TF_R(r) { x0 += x1; x1 = rotl32(x1, (r)); x1 ^= x0; }
    TF_R(13) TF_R(15) TF_R(26) TF_R(6)
    x0 += k1; x1 += k2 + 1u;
    TF_R(17) TF_R(29) TF_R(16) TF_R(24)
    x0 += k2; x1 += k0 + 2u;
    TF_R(13) TF_R(15) TF_R(26) TF_R(6)
    x0 += k0; x1 += k1 + 3u;
    TF_R(17) TF_R(29) TF_R(16) TF_R(24)
    x0 += k1; x1 += k2 + 4u;
    TF_R(13) TF_R(15) TF_R(26) TF_R(6)
    x0 += k2; x1 += k0 + 5u;
#undef TF_R
    o0 = x0; o1 = x1;
}

// ---------------------------------------------------------------------------
// CSR build: deg histogram, exclusive scan, scatter edge ids.
// dst_f[i] = dst[i] (i<NE) else src[i-NE]
// ---------------------------------------------------------------------------
__global__ void deg_kernel(const int* __restrict__ src, const int* __restrict__ dst,
                           int* __restrict__ deg) {
    int i = blockIdx.x * blockDim.x + threadIdx.x;
    if (i < NE2) {
        int n = (i < NE) ? dst[i] : src[i - NE];
        atomicAdd(&deg[n], 1);
    }
}

__global__ void prefix_kernel(const int* __restrict__ deg, int* __restrict__ row_start,
                              int* __restrict__ cursor) {
    __shared__ int sums[1024];
    int t = threadIdx.x;
    const int CH = (NN + 1023) / 1024;  // 20
    int lo = t * CH, hi = lo + CH;
    if (hi > NN) hi = NN;
    if (lo > NN) lo = NN;
    int s = 0;
    for (int n = lo; n < hi; n++) s += deg[n];
    sums[t] = s;
    __syncthreads();
    for (int off = 1; off < 1024; off <<= 1) {
        int v = (t >= off) ? sums[t - off] : 0;
        __syncthreads();
        sums[t] += v;
        __syncthreads();
    }
    int run = (t == 0) ? 0 : sums[t - 1];
    for (int n = lo; n < hi; n++) {
        row_start[n] = run;
        cursor[n] = run;
        run += deg[n];
    }
    if (t == 1023) row_start[NN] = sums[1023];
}

__global__ void scatter_kernel(const int* __restrict__ src, const int* __restrict__ dst,
                               int* __restrict__ cursor, int* __restrict__ elist) {
    int i = blockIdx.x * blockDim.x + threadIdx.x;
    if (i < NE2) {
        int n = (i < NE) ? dst[i] : src[i - NE];
        int pos = atomicAdd(&cursor[n], 1);
        elist[pos] = i;
    }
}

// ---------------------------------------------------------------------------
// Mean aggregation: one wave per node. lane holds features [4*lane, 4*lane+4).
// msg(i<NE)  = xin[src[i]] + edge_attr[i]
// msg(i>=NE) = xin[dst[i-NE]] + ea_rev[i-NE]
// ---------------------------------------------------------------------------
__global__ __launch_bounds__(64) void agg_kernel(
        const float* __restrict__ xin, const float* __restrict__ ea,
        const float* __restrict__ ea_rev,
        const int* __restrict__ src, const int* __restrict__ dst,
        const int* __restrict__ row_start, const int* __restrict__ elist,
        const int* __restrict__ deg, float* __restrict__ agg) {
    int n = blockIdx.x;
    int lane = threadIdx.x;
    float4 acc = make_float4(0.f, 0.f, 0.f, 0.f);
    int beg = row_start[n], end = row_start[n + 1];
    for (int p = beg; p < end; p++) {
        int i = elist[p];
        int sn;
        const float* er;
        if (i < NE) { sn = src[i]; er = ea + (size_t)i * EMB; }
        else        { int j = i - NE; sn = dst[j]; er = ea_rev + (size_t)j * EMB; }
        float4 xv = *(const float4*)(xin + (size_t)sn * EMB + lane * 4);
        float4 ev = *(const float4*)(er + lane * 4);
        acc.x += xv.x + ev.x; acc.y += xv.y + ev.y;
        acc.z += xv.z + ev.z; acc.w += xv.w + ev.w;
    }
    float d = fmaxf((float)deg[n], 1.0f);
    float4 o;
    o.x = acc.x / d; o.y = acc.y / d; o.z = acc.z / d; o.w = acc.w / d;
    *(float4*)(agg + (size_t)n * EMB + lane * 4) = o;
}

// ---------------------------------------------------------------------------
// Fused reverse-edge MLP: out = relu(ea @ W1 + b1) @ W2 + b2
// Tile: 32 edges per block; hidden tile lives in LDS.
// ---------------------------------------------------------------------------
__global__ __launch_bounds__(256) void rev_mlp_kernel(
        const float* __restrict__ ea,
        const float* __restrict__ W1, const float* __restrict__ b1,
        const float* __restrict__ W2, const float* __restrict__ b2,
        float* __restrict__ out) {
    __shared__ __attribute__((aligned(16))) float As[32][20];
    __shared__ __attribute__((aligned(16))) float Bs[16][EMB];
    __shared__ __attribute__((aligned(16))) float Hid[32][EMB + 4];
    int tid = threadIdx.x;
    int tx = tid & 15, ty = tid >> 4;  // ty 0..15, rows ty*2+i
    size_t row0 = (size_t)blockIdx.x * 32;

    float acc[2][16];
#pragma unroll
    for (int i = 0; i < 2; i++)
#pragma unroll
        for (int j = 0; j < 16; j++) acc[i][j] = 0.f;

    for (int k0 = 0; k0 < 256; k0 += 16) {
        __syncthreads();
        if (tid < 128) {
            const float* p = ea + (row0 + (tid >> 2)) * EMB + k0 + (tid & 3) * 4;
            *(float4*)&As[tid >> 2][(tid & 3) * 4] = *(const float4*)p;
        }
        {
            const float* wrow = W1 + (size_t)(k0 + (tid >> 4)) * EMB + (tid & 15) * 16;
            float* q = &Bs[tid >> 4][(tid & 15) * 16];
            *(float4*)(q + 0)  = *(const float4*)(wrow + 0);
            *(float4*)(q + 4)  = *(const float4*)(wrow + 4);
            *(float4*)(q + 8)  = *(const float4*)(wrow + 8);
            *(float4*)(q + 12) = *(const float4*)(wrow + 12);
        }
        __syncthreads();
#pragma unroll
        for (int kk = 0; kk < 16; kk++) {
            float a0 = As[ty * 2 + 0][kk];
            float a1 = As[ty * 2 + 1][kk];
#pragma unroll
            for (int j = 0; j < 16; j++) {
                float bv = Bs[kk][tx + 16 * j];
                acc[0][j] += a0 * bv;
                acc[1][j] += a1 * bv;
            }
        }
    }
    // bias + relu -> Hid
#pragma unroll
    for (int j = 0; j < 16; j++) {
        float bb = b1[tx + 16 * j];
        Hid[ty * 2 + 0][tx + 16 * j] = fmaxf(acc[0][j] + bb, 0.f);
        Hid[ty * 2 + 1][tx + 16 * j] = fmaxf(acc[1][j] + bb, 0.f);
    }

    float acc2[2][16];
#pragma unroll
    for (int i = 0; i < 2; i++)
#pragma unroll
        for (int j = 0; j < 16; j++) acc2[i][j] = 0.f;

    for (int k0 = 0; k0 < 256; k0 += 16) {
        __syncthreads();  // also orders Hid writes (above) vs reads (below)
        {
            const float* wrow = W2 + (size_t)(k0 + (tid >> 4)) * EMB + (tid & 15) * 16;
            float* q = &Bs[tid >> 4][(tid & 15) * 16];
            *(float4*)(q + 0)  = *(const float4*)(wrow + 0);
            *(float4*)(q + 4)  = *(const float4*)(wrow + 4);
            *(float4*)(q + 8)  = *(const float4*)(wrow + 8);
            *(float4*)(q + 12) = *(const float4*)(wrow + 12);
        }
        __syncthreads();
#pragma unroll
        for (int kk = 0; kk < 16; kk++) {
            float a0 = Hid[ty * 2 + 0][k0 + kk];
            float a1 = Hid[ty * 2 + 1][k0 + kk];
#pragma unroll
            for (int j = 0; j < 16; j++) {
                float bv = Bs[kk][tx + 16 * j];
                acc2[0][j] += a0 * bv;
                acc2[1][j] += a1 * bv;
            }
        }
    }
#pragma unroll
    for (int j = 0; j < 16; j++) {
        float bb = b2[tx + 16 * j];
        out[(row0 + ty * 2 + 0) * EMB + tx + 16 * j] = acc2[0][j] + bb;
        out[(row0 + ty * 2 + 1) * EMB + tx + 16 * j] = acc2[1][j] + bb;
    }
}

// ---------------------------------------------------------------------------
// SAGE linear: h = relu([xin | agg] @ W + b), M=NN, K=512, N=256
// ---------------------------------------------------------------------------
__global__ __launch_bounds__(256) void sage_gemm_kernel(
        const float* __restrict__ xin, const float* __restrict__ agg,
        const float* __restrict__ W, const float* __restrict__ b,
        float* __restrict__ h) {
    __shared__ __attribute__((aligned(16))) float As[64][20];
    __shared__ __attribute__((aligned(16))) float Bs[16][EMB];
    int tid = threadIdx.x;
    int tx = tid & 15, ty = tid >> 4;
    int row0 = blockIdx.x * 64;

    float acc[4][16];
#pragma unroll
    for (int i = 0; i < 4; i++)
#pragma unroll
        for (int j = 0; j < 16; j++) acc[i][j] = 0.f;

    for (int k0 = 0; k0 < 512; k0 += 16) {
        __syncthreads();
        {
            int r = row0 + (tid >> 2);
            int rc = r < NN ? r : NN - 1;
            const float* srcrow = (k0 < 256)
                ? (xin + (size_t)rc * EMB + k0)
                : (agg + (size_t)rc * EMB + (k0 - 256));
            *(float4*)&As[tid >> 2][(tid & 3) * 4] =
                *(const float4*)(srcrow + (tid & 3) * 4);
        }
        {
            const float* wrow = W + (size_t)(k0 + (tid >> 4)) * EMB + (tid & 15) * 16;
            float* q = &Bs[tid >> 4][(tid & 15) * 16];
            *(float4*)(q + 0)  = *(const float4*)(wrow + 0);
            *(float4*)(q + 4)  = *(const float4*)(wrow + 4);
            *(float4*)(q + 8)  = *(const float4*)(wrow + 8);
            *(float4*)(q + 12) = *(const float4*)(wrow + 12);
        }
        __syncthreads();
#pragma unroll
        for (int kk = 0; kk < 16; kk++) {
            float a[4];
#pragma unroll
            for (int i = 0; i < 4; i++) a[i] = As[ty * 4 + i][kk];
#pragma unroll
            for (int j = 0; j < 16; j++) {
                float bv = Bs[kk][tx + 16 * j];
#pragma unroll
                for (int i = 0; i < 4; i++) acc[i][j] += a[i] * bv;
            }
        }
    }
#pragma unroll
    for (int j = 0; j < 16; j++) {
        float bb = b[tx + 16 * j];
#pragma unroll
        for (int i = 0; i < 4; i++) {
            int r = row0 + ty * 4 + i;
            if (r < NN)
                h[(size_t)r * EMB + tx + 16 * j] = fmaxf(acc[i][j] + bb, 0.f);
        }
    }
}

// ---------------------------------------------------------------------------
// Prediction head, fused: per 64-edge tile
//   hidden = relu(h_triple @ W_pred1 + b_pred1)   (K=1536, N=256)
//   logit  = hidden . w2 + b2 ; sampled = sigmoid(logit + threefry noise)
// h_triple cols: [0:256)=q  [256:512)=h1[src] [512:768)=h2[src]
//                [768:1024)=ea [1024:1280)=h1[dst] [1280:1536)=h2[dst]
// ---------------------------------------------------------------------------
__global__ __launch_bounds__(256) void pred_kernel(
        const float* __restrict__ q, const float* __restrict__ ea,
        const float* __restrict__ h1, const float* __restrict__ h2,
        const int* __restrict__ src, const int* __restrict__ dst,
        const float* __restrict__ W1, const float* __restrict__ b1,
        const float* __restrict__ w2, const float* __restrict__ b2,
        float* __restrict__ out_logits, float* __restrict__ out_sampled) {
    __shared__ __attribute__((aligned(16))) float As[64][20];
    __shared__ __attribute__((aligned(16))) float Bs[16][EMB];
    __shared__ __attribute__((aligned(16))) float Ps[64][17];
    int tid = threadIdx.x;
    int tx = tid & 15, ty = tid >> 4;
    int row0 = blockIdx.x * 64;

    float acc[4][16];
#pragma unroll
    for (int i = 0; i < 4; i++)
#pragma unroll
        for (int j = 0; j < 16; j++) acc[i][j] = 0.f;

    for (int k0 = 0; k0 < 1536; k0 += 16) {
        __syncthreads();
        {
            int arow = tid >> 2;
            int e = row0 + arow;
            int seg = k0 >> 8;
            int off = (k0 & 255) + (tid & 3) * 4;
            const float* p;
            switch (seg) {
                case 0:  p = q  + (size_t)e * EMB + off; break;
                case 1:  p = h1 + (size_t)src[e] * EMB + off; break;
                case 2:  p = h2 + (size_t)src[e] * EMB + off; break;
                case 3:  p = ea + (size_t)e * EMB + off; break;
                case 4:  p = h1 + (size_t)dst[e] * EMB + off; break;
                default: p = h2 + (size_t)dst[e] * EMB + off; break;
            }
            *(float4*)&As[arow][(tid & 3) * 4] = *(const float4*)p;
        }
        {
            const float* wrow = W1 + (size_t)(k0 + (tid >> 4)) * EMB + (tid & 15) * 16;
            float* qd = &Bs[tid >> 4][(tid & 15) * 16];
            *(float4*)(qd + 0)  = *(const float4*)(wrow + 0);
            *(float4*)(qd + 4)  = *(const float4*)(wrow + 4);
            *(float4*)(qd + 8)  = *(const float4*)(wrow + 8);
            *(float4*)(qd + 12) = *(const float4*)(wrow + 12);
        }
        __syncthreads();
#pragma unroll
        for (int kk = 0; kk < 16; kk++) {
            float a[4];
#pragma unroll
            for (int i = 0; i < 4; i++) a[i] = As[ty * 4 + i][kk];
#pragma unroll
            for (int j = 0; j < 16; j++) {
                float bv = Bs[kk][tx + 16 * j];
#pragma unroll
                for (int i = 0; i < 4; i++) acc[i][j] += a[i] * bv;
            }
        }
    }
    // epilogue: bias + relu + dot with w2, reduce across tx
    float part[4] = {0.f, 0.f, 0.f, 0.f};
#pragma unroll
    for (int j = 0; j < 16; j++) {
        float bb = b1[tx + 16 * j];
        float wv = w2[tx + 16 * j];
#pragma unroll
        for (int i = 0; i < 4; i++) {
            float hh = fmaxf(acc[i][j] + bb, 0.f);
            part[i] += hh * wv;
        }
    }
    __syncthreads();
#pragma unroll
    for (int i = 0; i < 4; i++) Ps[ty * 4 + i][tx] = part[i];
    __syncthreads();
    if (tid < 64) {
        float s = 0.f;
#pragma unroll
        for (int t2 = 0; t2 < 16; t2++) s += Ps[tid][t2];
        float logit = s + b2[0];
        int e = row0 + tid;
        out_logits[e] = logit;
        // JAX threefry noise, partitionable mode (JAX >= 0.5 default):
        // bits = o0 ^ o1 of threefry((0,42), (0, e))
        unsigned y0, y1;
        threefry2x32(0u, 42u, 0u, (unsigned)e, y0, y1);
        unsigned bits = y0 ^ y1;
        float f = __uint_as_float((bits >> 9) | 0x3F800000u) - 1.0f;
        const float minv = 1e-10f;
        float u = fmaxf(minv, f + minv);  // span == 1.0f in fp32
        float noise = logf(u) - logf(1.0f - u);
        float z = logit + noise;
        out_sampled[e] = 1.0f / (1.0f + expf(-z));
    }
}

// ---------------------------------------------------------------------------
extern "C" void kernel_launch(void* const* d_in, const int* in_sizes, int n_in,
                              void* d_out, int out_size, void* d_ws, size_t ws_size,
                              hipStream_t stream) {
    const float* x        = (const float*)d_in[0];
    const float* ea       = (const float*)d_in[1];
    const float* qemb     = (const float*)d_in[2];
    const int*   eidx     = (const int*)d_in[3];
    const float* W_rev1   = (const float*)d_in[4];
    const float* b_rev1   = (const float*)d_in[5];
    const float* W_rev2   = (const float*)d_in[6];
    const float* b_rev2   = (const float*)d_in[7];
    const float* W_sage1  = (const float*)d_in[8];
    const float* b_sage1  = (const float*)d_in[9];
    const float* W_sage2  = (const float*)d_in[10];
    const float* b_sage2  = (const float*)d_in[11];
    const float* W_pred1  = (const float*)d_in[12];
    const float* b_pred1  = (const float*)d_in[13];
    const float* W_pred2  = (const float*)d_in[14];
    const float* b_pred2  = (const float*)d_in[15];
    float* out = (float*)d_out;

    const int* src = eidx;
    const int* dst = eidx + NE;

    char* w = (char*)d_ws;
    float* ea_rev    = (float*)w; w += (size_t)NE * EMB * sizeof(float);   // 204.8 MB
    float* aggbuf    = (float*)w; w += (size_t)NN * EMB * sizeof(float);   // 20.5 MB
    float* h1        = (float*)w; w += (size_t)NN * EMB * sizeof(float);   // 20.5 MB
    float* h2        = (float*)w; w += (size_t)NN * EMB * sizeof(float);   // 20.5 MB
    int*   deg       = (int*)w;   w += (size_t)NN * sizeof(int);
    int*   row_start = (int*)w;   w += (size_t)(NN + 1) * sizeof(int);
    int*   cursor    = (int*)w;   w += (size_t)NN * sizeof(int);
    int*   elist     = (int*)w;   w += (size_t)NE2 * sizeof(int);

    // CSR build (ws is re-poisoned before every call -> zero deg every call)
    hipMemsetAsync(deg, 0, (size_t)NN * sizeof(int), stream);
    deg_kernel<<<(NE2 + 255) / 256, 256, 0, stream>>>(src, dst, deg);
    prefix_kernel<<<1, 1024, 0, stream>>>(deg, row_start, cursor);
    scatter_kernel<<<(NE2 + 255) / 256, 256, 0, stream>>>(src, dst, cursor, elist);

    // reverse-edge MLP
    rev_mlp_kernel<<<NE / 32, 256, 0, stream>>>(ea, W_rev1, b_rev1, W_rev2, b_rev2, ea_rev);

    // SAGE layer 1
    agg_kernel<<<NN, 64, 0, stream>>>(x, ea, ea_rev, src, dst, row_start, elist, deg, aggbuf);
    sage_gemm_kernel<<<(NN + 63) / 64, 256, 0, stream>>>(x, aggbuf, W_sage1, b_sage1, h1);

    // SAGE layer 2
    agg_kernel<<<NN, 64, 0, stream>>>(h1, ea, ea_rev, src, dst, row_start, elist, deg, aggbuf);
    sage_gemm_kernel<<<(NN + 63) / 64, 256, 0, stream>>>(h1, aggbuf, W_sage2, b_sage2, h2);

    // prediction head + noise + sigmoid
    pred_kernel<<<NE / 64, 256, 0, stream>>>(qemb, ea, h1, h2, src, dst,
                                             W_pred1, b_pred1, W_pred2, b_pred2,
                                             out, out + NE);
}

// Round 3
// 1098.710 us; speedup vs baseline: 6.7547x; 6.7547x over previous
//
#include <hip/hip_runtime.h>
#include <cstdint>
#include <cstddef>

#define EMB 256
#define NN 20000
#define NE 200000
#define NE2 400000

typedef unsigned short ushort_t;
typedef __attribute__((ext_vector_type(8))) short bf16x8;
typedef __attribute__((ext_vector_type(4))) float f32x4;

// ---------------------------------------------------------------------------
// bf16 helpers (RNE)
// ---------------------------------------------------------------------------
__device__ __forceinline__ ushort_t f2bf(float f) {
    unsigned u = __float_as_uint(f);
    u += 0x7FFFu + ((u >> 16) & 1u);
    return (ushort_t)(u >> 16);
}
__device__ __forceinline__ float bf2f(ushort_t u) {
    return __uint_as_float(((unsigned)u) << 16);
}

// async global->LDS, 16B per lane. LDS dest = wave-uniform base + lane*16.
__device__ __forceinline__ void async_cp16(const ushort_t* g, ushort_t* l) {
    __builtin_amdgcn_global_load_lds(
        (const __attribute__((address_space(1))) unsigned int*)g,
        (__attribute__((address_space(3))) unsigned int*)l,
        16, 0, 0);
}

// ---------------------------------------------------------------------------
// Threefry2x32, partitionable mode: bits(e) = o0^o1 of threefry((0,42),(0,e))
// ---------------------------------------------------------------------------
__device__ __forceinline__ unsigned rotl32(unsigned v, int d) {
    return (v << d) | (v >> (32 - d));
}
__device__ __forceinline__ void threefry2x32(unsigned k0, unsigned k1,
                                             unsigned x0, unsigned x1,
                                             unsigned& o0, unsigned& o1) {
    unsigned k2 = k0 ^ k1 ^ 0x1BD11BDAu;
    x0 += k0; x1 += k1;
#define TF_R(r) { x0 += x1; x1 = rotl32(x1, (r)); x1 ^= x0; }
    TF_R(13) TF_R(15) TF_R(26) TF_R(6)
    x0 += k1; x1 += k2 + 1u;
    TF_R(17) TF_R(29) TF_R(16) TF_R(24)
    x0 += k2; x1 += k0 + 2u;
    TF_R(13) TF_R(15) TF_R(26) TF_R(6)
    x0 += k0; x1 += k1 + 3u;
    TF_R(17) TF_R(29) TF_R(16) TF_R(24)
    x0 += k1; x1 += k2 + 4u;
    TF_R(13) TF_R(15) TF_R(26) TF_R(6)
    x0 += k2; x1 += k0 + 5u;
#undef TF_R
    o0 = x0; o1 = x1;
}

// ---------------------------------------------------------------------------
// CSR build
// ---------------------------------------------------------------------------
__global__ void deg_kernel(const int* __restrict__ src, const int* __restrict__ dst,
                           int* __restrict__ deg) {
    int i = blockIdx.x * blockDim.x + threadIdx.x;
    if (i < NE2) {
        int n = (i < NE) ? dst[i] : src[i - NE];
        atomicAdd(&deg[n], 1);
    }
}

__global__ void prefix_kernel(const int* __restrict__ deg, int* __restrict__ row_start,
                              int* __restrict__ cursor) {
    __shared__ int sums[1024];
    int t = threadIdx.x;
    const int CH = (NN + 1023) / 1024;
    int lo = t * CH, hi = lo + CH;
    if (hi > NN) hi = NN;
    if (lo > NN) lo = NN;
    int s = 0;
    for (int n = lo; n < hi; n++) s += deg[n];
    sums[t] = s;
    __syncthreads();
    for (int off = 1; off < 1024; off <<= 1) {
        int v = (t >= off) ? sums[t - off] : 0;
        __syncthreads();
        sums[t] += v;
        __syncthreads();
    }
    int run = (t == 0) ? 0 : sums[t - 1];
    for (int n = lo; n < hi; n++) {
        row_start[n] = run;
        cursor[n] = run;
        run += deg[n];
    }
    if (t == 1023) row_start[NN] = sums[1023];
}

__global__ void scatter_kernel(const int* __restrict__ src, const int* __restrict__ dst,
                               int* __restrict__ cursor, int* __restrict__ elist) {
    int i = blockIdx.x * blockDim.x + threadIdx.x;
    if (i < NE2) {
        int n = (i < NE) ? dst[i] : src[i - NE];
        int pos = atomicAdd(&cursor[n], 1);
        elist[pos] = i;
    }
}

// ---------------------------------------------------------------------------
// fp32 -> bf16 bulk convert (n8 = count/8 items)
// ---------------------------------------------------------------------------
__global__ void conv_bf_kernel(const float* __restrict__ in, ushort_t* __restrict__ out,
                               int n8) {
    int i = blockIdx.x * 256 + threadIdx.x;
    if (i >= n8) return;
    const float* p = in + (size_t)i * 8;
    float4 a = *(const float4*)p;
    float4 b = *(const float4*)(p + 4);
    union { ushort_t u[8]; uint4 v; } r;
    r.u[0] = f2bf(a.x); r.u[1] = f2bf(a.y); r.u[2] = f2bf(a.z); r.u[3] = f2bf(a.w);
    r.u[4] = f2bf(b.x); r.u[5] = f2bf(b.y); r.u[6] = f2bf(b.z); r.u[7] = f2bf(b.w);
    *(uint4*)(out + (size_t)i * 8) = r.v;
}

// ---------------------------------------------------------------------------
// Weight transpose+convert: dst[n*dstStride + koff + k] = bf16(src[k*256 + n])
// grid = Krows blocks of 256 threads
// ---------------------------------------------------------------------------
__global__ void transpose_bf_kernel(const float* __restrict__ src, ushort_t* __restrict__ dst,
                                    int dstStride, int koff, int Krows) {
    int k = blockIdx.x;
    int n = threadIdx.x;
    dst[(size_t)n * dstStride + koff + k] = f2bf(src[(size_t)k * 256 + n]);
}

// ---------------------------------------------------------------------------
// Generic bf16 MFMA GEMM: C[M x 256] = A[M x KTOT] @ B[KTOT x 256]
//  A given as two k-segments (seg0: k<256 at A0/rsA0, seg1: k>=256 at A1/rsA1).
//  Bt is [256][KTOT] bf16 (n-major, k contiguous).
//  Tile: 128 rows x full 256 cols per block; 4 waves in 2x2; BK=32.
//  EPI: 0 = fp32 store, 1 = bf16, 2 = bf16+bias, 3 = bf16+bias+relu
// ---------------------------------------------------------------------------
template <int KTOT, int EPI>
__global__ __launch_bounds__(256, 2) void mfma_gemm(
        const ushort_t* __restrict__ A0, int rsA0,
        const ushort_t* __restrict__ A1, int rsA1,
        const ushort_t* __restrict__ Bt,
        const float* __restrict__ bias,
        void* __restrict__ out, int rsOut, int M) {
    __shared__ ushort_t As[128 * 32];   // [row][k] row stride 32
    __shared__ ushort_t Bs[256 * 32];   // [n][k]  row stride 32

    int tid = threadIdx.x;
    int lane = tid & 63;
    int wave = tid >> 6;          // 0..3
    int wr = wave >> 1;           // row half (64 rows)
    int wc = wave & 1;            // col half (128 cols)
    int quad = lane >> 4;
    int col_l = lane & 15;
    int bm = blockIdx.x;

    f32x4 acc[4][8];
#pragma unroll
    for (int mt = 0; mt < 4; mt++)
#pragma unroll
        for (int nt = 0; nt < 8; nt++) acc[mt][nt] = (f32x4)0.f;

    for (int k0 = 0; k0 < KTOT; k0 += 32) {
        __syncthreads();  // protect LDS from previous iteration's readers
        // --- stage A tile: 128 rows x 32 k (bf16) via global_load_lds x2 ---
        const ushort_t* abase;
        int rs, koffs;
        if (KTOT == 512 && k0 >= 256) { abase = A1; rs = rsA1; koffs = k0 - 256; }
        else                          { abase = A0; rs = rsA0; koffs = k0; }
#pragma unroll
        for (int j = 0; j < 2; j++) {
            int flat = tid + 256 * j;
            int row = flat >> 2, ch = flat & 3;
            int grow = bm * 128 + row;
            if (grow >= M) grow = M - 1;
            const ushort_t* gp = abase + (size_t)grow * rs + koffs + ch * 8;
            ushort_t* lp = As + ((wave * 64 + 256 * j) * 8);  // *16B == *8 ushorts... (16B per flat)
            async_cp16(gp, lp);
        }
        // --- stage B tile: 256 n-rows x 32 k via global_load_lds x4 ---
#pragma unroll
        for (int j = 0; j < 4; j++) {
            int flat = tid + 256 * j;
            int n = flat >> 2, ch = flat & 3;
            const ushort_t* gp = Bt + (size_t)n * KTOT + k0 + ch * 8;
            ushort_t* lp = Bs + ((wave * 64 + 256 * j) * 8);
            async_cp16(gp, lp);
        }
        __syncthreads();  // drains vmcnt (global_load_lds) per barrier semantics

        // --- fragments + MFMA ---
        bf16x8 a[4], b[8];
#pragma unroll
        for (int mt = 0; mt < 4; mt++)
            a[mt] = *(const bf16x8*)(As + (wr * 64 + mt * 16 + col_l) * 32 + quad * 8);
#pragma unroll
        for (int nt = 0; nt < 8; nt++)
            b[nt] = *(const bf16x8*)(Bs + (wc * 128 + nt * 16 + col_l) * 32 + quad * 8);
#pragma unroll
        for (int mt = 0; mt < 4; mt++)
#pragma unroll
            for (int nt = 0; nt < 8; nt++)
                acc[mt][nt] = __builtin_amdgcn_mfma_f32_16x16x32_bf16(
                    a[mt], b[nt], acc[mt][nt], 0, 0, 0);
    }

    // --- epilogue ---
    float bs[8];
    if (EPI >= 2) {
#pragma unroll
        for (int nt = 0; nt < 8; nt++) bs[nt] = bias[wc * 128 + nt * 16 + col_l];
    }
#pragma unroll
    for (int mt = 0; mt < 4; mt++) {
#pragma unroll
        for (int nt = 0; nt < 8; nt++) {
            int colg = wc * 128 + nt * 16 + col_l;
#pragma unroll
            for (int r = 0; r < 4; r++) {
                int rg = bm * 128 + wr * 64 + mt * 16 + quad * 4 + r;
                if (rg < M) {
                    float v = acc[mt][nt][r];
                    if (EPI >= 2) v += bs[nt];
                    if (EPI == 3) v = fmaxf(v, 0.f);
                    if (EPI == 0)
                        ((float*)out)[(size_t)rg * rsOut + colg] = v;
                    else
                        ((ushort_t*)out)[(size_t)rg * rsOut + colg] = f2bf(v);
                }
            }
        }
    }
}

// ---------------------------------------------------------------------------
// Mean aggregation over bf16 features. One wave per node; lane owns 4 cols.
// xin row stride rsx (256 for x_bf, 512 for H(h1)).
// ---------------------------------------------------------------------------
__global__ __launch_bounds__(64) void agg_bf_kernel(
        const ushort_t* __restrict__ xin, int rsx,
        const ushort_t* __restrict__ eaf, const ushort_t* __restrict__ ear,
        const int* __restrict__ src, const int* __restrict__ dst,
        const int* __restrict__ row_start, const int* __restrict__ elist,
        const int* __restrict__ deg, ushort_t* __restrict__ agg) {
    int n = blockIdx.x;
    int c = threadIdx.x * 4;
    float ax = 0.f, ay = 0.f, az = 0.f, aw = 0.f;
    int beg = row_start[n], end = row_start[n + 1];
    for (int p = beg; p < end; p++) {
        int i = elist[p];
        const ushort_t* xr;
        const ushort_t* er;
        if (i < NE) { xr = xin + (size_t)src[i] * rsx; er = eaf + (size_t)i * 256; }
        else { int j = i - NE; xr = xin + (size_t)dst[j] * rsx; er = ear + (size_t)j * 256; }
        ushort4 xv = *(const ushort4*)(xr + c);
        ushort4 ev = *(const ushort4*)(er + c);
        ax += bf2f(xv.x) + bf2f(ev.x);
        ay += bf2f(xv.y) + bf2f(ev.y);
        az += bf2f(xv.z) + bf2f(ev.z);
        aw += bf2f(xv.w) + bf2f(ev.w);
    }
    float d = fmaxf((float)deg[n], 1.0f);
    ushort4 o;
    o.x = f2bf(ax / d); o.y = f2bf(ay / d); o.z = f2bf(az / d); o.w = f2bf(aw / d);
    *(ushort4*)(agg + (size_t)n * 256 + c) = o;
}

// ---------------------------------------------------------------------------
// Finish: logit[e] = w2 . relu(edge_pre[e] + Hsrc[src[e]] + Hdst[dst[e]] + b1) + b2
// sampled[e] = sigmoid(logit + logistic threefry noise). 4 edges / 256-block.
// ---------------------------------------------------------------------------
__global__ __launch_bounds__(256) void finish_kernel(
        const ushort_t* __restrict__ pre,
        const float* __restrict__ Hs, const float* __restrict__ Hd,
        const int* __restrict__ src, const int* __restrict__ dst,
        const float* __restrict__ b1, const float* __restrict__ w2,
        const float* __restrict__ b2,
        float* __restrict__ out_logits, float* __restrict__ out_sampled) {
    int e = blockIdx.x * 4 + (threadIdx.x >> 6);
    int lane = threadIdx.x & 63;
    int c = lane * 4;
    int s = src[e], d = dst[e];
    ushort4 p4 = *(const ushort4*)(pre + (size_t)e * 256 + c);
    float4 hs = *(const float4*)(Hs + (size_t)s * 256 + c);
    float4 hd = *(const float4*)(Hd + (size_t)d * 256 + c);
    float4 bb = *(const float4*)(b1 + c);
    float4 ww = *(const float4*)(w2 + c);
    float part =
        fmaxf(bf2f(p4.x) + hs.x + hd.x + bb.x, 0.f) * ww.x +
        fmaxf(bf2f(p4.y) + hs.y + hd.y + bb.y, 0.f) * ww.y +
        fmaxf(bf2f(p4.z) + hs.z + hd.z + bb.z, 0.f) * ww.z +
        fmaxf(bf2f(p4.w) + hs.w + hd.w + bb.w, 0.f) * ww.w;
#pragma unroll
    for (int m = 32; m > 0; m >>= 1) part += __shfl_xor(part, m, 64);
    if (lane == 0) {
        float logit = part + b2[0];
        out_logits[e] = logit;
        unsigned y0, y1;
        threefry2x32(0u, 42u, 0u, (unsigned)e, y0, y1);
        unsigned bits = y0 ^ y1;
        float f = __uint_as_float((bits >> 9) | 0x3F800000u) - 1.0f;
        float u = fmaxf(1e-10f, f + 1e-10f);
        float noise = logf(u) - logf(1.0f - u);
        out_sampled[e] = 1.0f / (1.0f + expf(-(logit + noise)));
    }
}

// ---------------------------------------------------------------------------
extern "C" void kernel_launch(void* const* d_in, const int* in_sizes, int n_in,
                              void* d_out, int out_size, void* d_ws, size_t ws_size,
                              hipStream_t stream) {
    const float* x        = (const float*)d_in[0];
    const float* ea       = (const float*)d_in[1];
    const float* qemb     = (const float*)d_in[2];
    const int*   eidx     = (const int*)d_in[3];
    const float* W_rev1   = (const float*)d_in[4];
    const float* b_rev1   = (const float*)d_in[5];
    const float* W_rev2   = (const float*)d_in[6];
    const float* b_rev2   = (const float*)d_in[7];
    const float* W_sage1  = (const float*)d_in[8];
    const float* b_sage1  = (const float*)d_in[9];
    const float* W_sage2  = (const float*)d_in[10];
    const float* b_sage2  = (const float*)d_in[11];
    const float* W_pred1  = (const float*)d_in[12];
    const float* b_pred1  = (const float*)d_in[13];
    const float* W_pred2  = (const float*)d_in[14];
    const float* b_pred2  = (const float*)d_in[15];
    float* out = (float*)d_out;

    const int* src = eidx;
    const int* dst = eidx + NE;

    // ---- workspace layout (~392 MB) ----
    char* w = (char*)d_ws;
    ushort_t* ea_bf  = (ushort_t*)w; w += (size_t)NE * 256 * 2;   // 102.4 MB
    ushort_t* slotA  = (ushort_t*)w; w += (size_t)NE * 256 * 2;   // hid_bf -> edge_pre
    ushort_t* slotB  = (ushort_t*)w; w += (size_t)NE * 256 * 2;   // ea_rev_bf -> q_bf
    ushort_t* x_bf   = (ushort_t*)w; w += (size_t)NN * 256 * 2;   // 10.2 MB
    ushort_t* H      = (ushort_t*)w; w += (size_t)NN * 512 * 2;   // [h1|h2] 20.5 MB
    ushort_t* agg_bf = (ushort_t*)w; w += (size_t)NN * 256 * 2;   // 10.2 MB
    float*    Hsrc   = (float*)w;    w += (size_t)NN * 256 * 4;   // 20.5 MB
    float*    Hdst   = (float*)w;    w += (size_t)NN * 256 * 4;   // 20.5 MB
    ushort_t* Wt_rev1  = (ushort_t*)w; w += 256 * 256 * 2;
    ushort_t* Wt_rev2  = (ushort_t*)w; w += 256 * 256 * 2;
    ushort_t* Wt_sage1 = (ushort_t*)w; w += 256 * 512 * 2;
    ushort_t* Wt_sage2 = (ushort_t*)w; w += 256 * 512 * 2;
    ushort_t* Wt_src   = (ushort_t*)w; w += 256 * 512 * 2;
    ushort_t* Wt_dst   = (ushort_t*)w; w += 256 * 512 * 2;
    ushort_t* Wt_edge  = (ushort_t*)w; w += 256 * 512 * 2;
    int* deg       = (int*)w; w += (size_t)NN * 4;
    int* row_start = (int*)w; w += (size_t)(NN + 1) * 4;
    int* cursor    = (int*)w; w += (size_t)NN * 4;
    int* elist     = (int*)w; w += (size_t)NE2 * 4;

    ushort_t* hid_bf    = slotA;
    ushort_t* edge_pre  = slotA;   // alias: hid dead after G_rev
    ushort_t* ea_rev_bf = slotB;
    ushort_t* q_bf      = slotB;   // alias: ea_rev dead after agg2

    const int EB = (NE + 127) / 128;   // 1563
    const int NB = (NN + 127) / 128;   // 157

    // ---- CSR ----
    hipMemsetAsync(deg, 0, (size_t)NN * 4, stream);
    deg_kernel<<<(NE2 + 255) / 256, 256, 0, stream>>>(src, dst, deg);
    prefix_kernel<<<1, 1024, 0, stream>>>(deg, row_start, cursor);
    scatter_kernel<<<(NE2 + 255) / 256, 256, 0, stream>>>(src, dst, cursor, elist);

    // ---- weight transposes (bf16 [N][K]) ----
    transpose_bf_kernel<<<256, 256, 0, stream>>>(W_rev1, Wt_rev1, 256, 0, 256);
    transpose_bf_kernel<<<256, 256, 0, stream>>>(W_rev2, Wt_rev2, 256, 0, 256);
    transpose_bf_kernel<<<512, 256, 0, stream>>>(W_sage1, Wt_sage1, 512, 0, 512);
    transpose_bf_kernel<<<512, 256, 0, stream>>>(W_sage2, Wt_sage2, 512, 0, 512);
    transpose_bf_kernel<<<512, 256, 0, stream>>>(W_pred1 + (size_t)256 * 256, Wt_src, 512, 0, 512);
    transpose_bf_kernel<<<512, 256, 0, stream>>>(W_pred1 + (size_t)1024 * 256, Wt_dst, 512, 0, 512);
    transpose_bf_kernel<<<256, 256, 0, stream>>>(W_pred1, Wt_edge, 512, 0, 256);
    transpose_bf_kernel<<<256, 256, 0, stream>>>(W_pred1 + (size_t)768 * 256, Wt_edge, 512, 256, 256);

    // ---- activations to bf16 ----
    conv_bf_kernel<<<(NE * 256 / 8 + 255) / 256, 256, 0, stream>>>(ea, ea_bf, NE * 256 / 8);
    conv_bf_kernel<<<(NN * 256 / 8 + 255) / 256, 256, 0, stream>>>(x, x_bf, NN * 256 / 8);

    // ---- reverse-edge MLP (bf16 MFMA) ----
    mfma_gemm<256, 3><<<EB, 256, 0, stream>>>(ea_bf, 256, nullptr, 0, Wt_rev1, b_rev1,
                                              hid_bf, 256, NE);
    mfma_gemm<256, 2><<<EB, 256, 0, stream>>>(hid_bf, 256, nullptr, 0, Wt_rev2, b_rev2,
                                              ea_rev_bf, 256, NE);

    // ---- SAGE layer 1 ----
    agg_bf_kernel<<<NN, 64, 0, stream>>>(x_bf, 256, ea_bf, ea_rev_bf,
                                         src, dst, row_start, elist, deg, agg_bf);
    mfma_gemm<512, 3><<<NB, 256, 0, stream>>>(x_bf, 256, agg_bf, 256, Wt_sage1, b_sage1,
                                              H, 512, NN);          // h1 -> H[:,0:256)
    // ---- SAGE layer 2 ----
    agg_bf_kernel<<<NN, 64, 0, stream>>>(H, 512, ea_bf, ea_rev_bf,
                                         src, dst, row_start, elist, deg, agg_bf);
    mfma_gemm<512, 3><<<NB, 256, 0, stream>>>(H, 512, agg_bf, 256, Wt_sage2, b_sage2,
                                              H + 256, 512, NN);    // h2 -> H[:,256:512)

    // ---- node-side pred contributions (fp32 out) ----
    mfma_gemm<512, 0><<<NB, 256, 0, stream>>>(H, 512, H + 256, 512, Wt_src, nullptr,
                                              Hsrc, 256, NN);
    mfma_gemm<512, 0><<<NB, 256, 0, stream>>>(H, 512, H + 256, 512, Wt_dst, nullptr,
                                              Hdst, 256, NN);

    // ---- edge-side pred GEMM: q@W1a + ea@W1d ----
    conv_bf_kernel<<<(NE * 256 / 8 + 255) / 256, 256, 0, stream>>>(qemb, q_bf, NE * 256 / 8);
    mfma_gemm<512, 1><<<EB, 256, 0, stream>>>(q_bf, 256, ea_bf, 256, Wt_edge, nullptr,
                                              edge_pre, 256, NE);

    // ---- finish: gather + relu + dot + noise ----
    finish_kernel<<<NE / 4, 256, 0, stream>>>(edge_pre, Hsrc, Hdst, src, dst,
                                              b_pred1, W_pred2, b_pred2,
                                              out, out + NE);
}

// Round 4
// 1008.176 us; speedup vs baseline: 7.3613x; 1.0898x over previous
//
#include <hip/hip_runtime.h>
#include <cstdint>
#include <cstddef>

#define EMB 256
#define NN 20000
#define NE 200000
#define NE2 400000

typedef unsigned short ushort_t;
typedef __attribute__((ext_vector_type(8))) short bf16x8;
typedef __attribute__((ext_vector_type(4))) float f32x4;

// ---------------------------------------------------------------------------
// bf16 helpers (RNE)
// ---------------------------------------------------------------------------
__device__ __forceinline__ ushort_t f2bf(float f) {
    unsigned u = __float_as_uint(f);
    u += 0x7FFFu + ((u >> 16) & 1u);
    return (ushort_t)(u >> 16);
}
__device__ __forceinline__ float bf2f(ushort_t u) {
    return __uint_as_float(((unsigned)u) << 16);
}

// async global->LDS, 16B per lane. LDS dest = wave-uniform base + lane*16.
__device__ __forceinline__ void async_cp16(const ushort_t* g, ushort_t* l) {
    __builtin_amdgcn_global_load_lds(
        (const __attribute__((address_space(1))) unsigned int*)g,
        (__attribute__((address_space(3))) unsigned int*)l,
        16, 0, 0);
}

// ---------------------------------------------------------------------------
// Threefry2x32, partitionable mode: bits(e) = o0^o1 of threefry((0,42),(0,e))
// ---------------------------------------------------------------------------
__device__ __forceinline__ unsigned rotl32(unsigned v, int d) {
    return (v << d) | (v >> (32 - d));
}
__device__ __forceinline__ void threefry2x32(unsigned k0, unsigned k1,
                                             unsigned x0, unsigned x1,
                                             unsigned& o0, unsigned& o1) {
    unsigned k2 = k0 ^ k1 ^ 0x1BD11BDAu;
    x0 += k0; x1 += k1;
#define TF_R(r) { x0 += x1; x1 = rotl32(x1, (r)); x1 ^= x0; }
    TF_R(13) TF_R(15) TF_R(26) TF_R(6)
    x0 += k1; x1 += k2 + 1u;
    TF_R(17) TF_R(29) TF_R(16) TF_R(24)
    x0 += k2; x1 += k0 + 2u;
    TF_R(13) TF_R(15) TF_R(26) TF_R(6)
    x0 += k0; x1 += k1 + 3u;
    TF_R(17) TF_R(29) TF_R(16) TF_R(24)
    x0 += k1; x1 += k2 + 4u;
    TF_R(13) TF_R(15) TF_R(26) TF_R(6)
    x0 += k2; x1 += k0 + 5u;
#undef TF_R
    o0 = x0; o1 = x1;
}

// ---------------------------------------------------------------------------
// CSR build
// ---------------------------------------------------------------------------
__global__ void deg_kernel(const int* __restrict__ src, const int* __restrict__ dst,
                           int* __restrict__ deg) {
    int i = blockIdx.x * blockDim.x + threadIdx.x;
    if (i < NE2) {
        int n = (i < NE) ? dst[i] : src[i - NE];
        atomicAdd(&deg[n], 1);
    }
}

__global__ void prefix_kernel(const int* __restrict__ deg, int* __restrict__ row_start,
                              int* __restrict__ cursor) {
    __shared__ int sums[1024];
    int t = threadIdx.x;
    const int CH = (NN + 1023) / 1024;
    int lo = t * CH, hi = lo + CH;
    if (hi > NN) hi = NN;
    if (lo > NN) lo = NN;
    int s = 0;
    for (int n = lo; n < hi; n++) s += deg[n];
    sums[t] = s;
    __syncthreads();
    for (int off = 1; off < 1024; off <<= 1) {
        int v = (t >= off) ? sums[t - off] : 0;
        __syncthreads();
        sums[t] += v;
        __syncthreads();
    }
    int run = (t == 0) ? 0 : sums[t - 1];
    for (int n = lo; n < hi; n++) {
        row_start[n] = run;
        cursor[n] = run;
        run += deg[n];
    }
    if (t == 1023) row_start[NN] = sums[1023];
}

__global__ void scatter_kernel(const int* __restrict__ src, const int* __restrict__ dst,
                               int* __restrict__ cursor, int* __restrict__ elist) {
    int i = blockIdx.x * blockDim.x + threadIdx.x;
    if (i < NE2) {
        int n = (i < NE) ? dst[i] : src[i - NE];
        int pos = atomicAdd(&cursor[n], 1);
        elist[pos] = i;
    }
}

// ---------------------------------------------------------------------------
// fp32 -> bf16 bulk convert, two arrays in one launch
// ---------------------------------------------------------------------------
__global__ void conv2_kernel(const float* __restrict__ a, ushort_t* __restrict__ oa, int na8,
                             const float* __restrict__ b, ushort_t* __restrict__ ob, int nb8) {
    int i = blockIdx.x * 256 + threadIdx.x;
    const float* p;
    ushort_t* o;
    if (i < na8) { p = a + (size_t)i * 8; o = oa + (size_t)i * 8; }
    else {
        int j = i - na8;
        if (j >= nb8) return;
        p = b + (size_t)j * 8; o = ob + (size_t)j * 8;
    }
    float4 u = *(const float4*)p;
    float4 v = *(const float4*)(p + 4);
    union { ushort_t s[8]; uint4 w; } r;
    r.s[0] = f2bf(u.x); r.s[1] = f2bf(u.y); r.s[2] = f2bf(u.z); r.s[3] = f2bf(u.w);
    r.s[4] = f2bf(v.x); r.s[5] = f2bf(v.y); r.s[6] = f2bf(v.z); r.s[7] = f2bf(v.w);
    *(uint4*)o = r.w;
}

// ---------------------------------------------------------------------------
// All weight transposes in one launch. dst[n*stride + koff + k] = bf16(src[k*256+n])
// ---------------------------------------------------------------------------
struct TD { const float* src; ushort_t* dst; int stride, koff, kr; };
struct TA { TD d[8]; };

__global__ void transpose_all_kernel(TA ta) {
    TD t = ta.d[blockIdx.y];
    int k = blockIdx.x;
    if (k >= t.kr) return;
    int n = threadIdx.x;
    t.dst[(size_t)n * t.stride + t.koff + k] = f2bf(t.src[(size_t)k * 256 + n]);
}

// ---------------------------------------------------------------------------
// Generic bf16 MFMA GEMM: C[M x 256] = A[M x KTOT] @ B[KTOT x 256]
//  A seg0 (k<256): bf16 (A0F32=false) or fp32 (A0F32=true, converted in staging).
//  A seg1 (k>=256, KTOT==512): bf16 at A1/rsA1.
//  Bt/out selected by blockIdx.y (Bt2/out2) for paired launches.
//  Tile: 128 rows x 256 cols, 4 waves 2x2, BK=32.
//  EPI: 0 fp32 store, 1 bf16, 2 bf16+bias, 3 bf16+bias+relu,
//       4 fused pred head: logit = w2 . relu(acc + Hs[src] + Hd[dst] + bias) + b2;
//         out=logits, out_s=sigmoid(logit+threefry logistic noise)
// ---------------------------------------------------------------------------
template <int KTOT, int EPI, bool A0F32>
__global__ __launch_bounds__(256, 2) void mfma_gemm(
        const void* __restrict__ A0v, int rsA0,
        const ushort_t* __restrict__ A1, int rsA1,
        const ushort_t* __restrict__ Bt, const ushort_t* __restrict__ Bt2,
        const float* __restrict__ bias,
        void* __restrict__ out, void* __restrict__ out2, int rsOut, int M,
        const int* __restrict__ srcp, const int* __restrict__ dstp,
        const float* __restrict__ Hs, const float* __restrict__ Hd,
        const float* __restrict__ w2, const float* __restrict__ b2v,
        float* __restrict__ out_s) {
    __shared__ ushort_t As[128 * 32];   // [row][k] row stride 32
    __shared__ ushort_t Bs[256 * 32];   // [n][k]  row stride 32
    __shared__ float red[128];

    int tid = threadIdx.x;
    int lane = tid & 63;
    int wave = tid >> 6;
    int wr = wave >> 1;
    int wc = wave & 1;
    int quad = lane >> 4;
    int col_l = lane & 15;
    int bm = blockIdx.x;

    const ushort_t* Bsel = blockIdx.y ? Bt2 : Bt;
    void* Osel = blockIdx.y ? out2 : out;

    f32x4 acc[4][8];
#pragma unroll
    for (int mt = 0; mt < 4; mt++)
#pragma unroll
        for (int nt = 0; nt < 8; nt++) acc[mt][nt] = (f32x4)0.f;

    for (int k0 = 0; k0 < KTOT; k0 += 32) {
        __syncthreads();
        bool seg1 = (KTOT == 512) && (k0 >= 256);
        if (A0F32 && !seg1) {
            // fp32 A: load 32B, convert, ds_write 16B (same layout as async path)
#pragma unroll
            for (int j = 0; j < 2; j++) {
                int flat = tid + 256 * j;
                int row = flat >> 2, ch = flat & 3;
                int grow = bm * 128 + row;
                if (grow >= M) grow = M - 1;
                const float* gp = (const float*)A0v + (size_t)grow * rsA0 + k0 + ch * 8;
                float4 u = *(const float4*)gp;
                float4 v = *(const float4*)(gp + 4);
                union { ushort_t s[8]; uint4 w; } r;
                r.s[0] = f2bf(u.x); r.s[1] = f2bf(u.y); r.s[2] = f2bf(u.z); r.s[3] = f2bf(u.w);
                r.s[4] = f2bf(v.x); r.s[5] = f2bf(v.y); r.s[6] = f2bf(v.z); r.s[7] = f2bf(v.w);
                *(uint4*)(As + (size_t)flat * 8) = r.w;
            }
        } else {
            const ushort_t* abase;
            int rs, koffs;
            if (seg1) { abase = A1; rs = rsA1; koffs = k0 - 256; }
            else      { abase = (const ushort_t*)A0v; rs = rsA0; koffs = k0; }
#pragma unroll
            for (int j = 0; j < 2; j++) {
                int flat = tid + 256 * j;
                int row = flat >> 2, ch = flat & 3;
                int grow = bm * 128 + row;
                if (grow >= M) grow = M - 1;
                const ushort_t* gp = abase + (size_t)grow * rs + koffs + ch * 8;
                ushort_t* lp = As + ((wave * 64 + 256 * j) * 8);
                async_cp16(gp, lp);
            }
        }
#pragma unroll
        for (int j = 0; j < 4; j++) {
            int flat = tid + 256 * j;
            int n = flat >> 2, ch = flat & 3;
            const ushort_t* gp = Bsel + (size_t)n * KTOT + k0 + ch * 8;
            ushort_t* lp = Bs + ((wave * 64 + 256 * j) * 8);
            async_cp16(gp, lp);
        }
        __syncthreads();

        bf16x8 a[4], b[8];
#pragma unroll
        for (int mt = 0; mt < 4; mt++)
            a[mt] = *(const bf16x8*)(As + (wr * 64 + mt * 16 + col_l) * 32 + quad * 8);
#pragma unroll
        for (int nt = 0; nt < 8; nt++)
            b[nt] = *(const bf16x8*)(Bs + (wc * 128 + nt * 16 + col_l) * 32 + quad * 8);
#pragma unroll
        for (int mt = 0; mt < 4; mt++)
#pragma unroll
            for (int nt = 0; nt < 8; nt++)
                acc[mt][nt] = __builtin_amdgcn_mfma_f32_16x16x32_bf16(
                    a[mt], b[nt], acc[mt][nt], 0, 0, 0);
    }

    if (EPI == 4) {
        // fused pred head epilogue
        if (tid < 128) red[tid] = 0.f;
        __syncthreads();
        float b1c[8], w2c[8];
#pragma unroll
        for (int nt = 0; nt < 8; nt++) {
            int col = wc * 128 + nt * 16 + col_l;
            b1c[nt] = bias[col];
            w2c[nt] = w2[col];
        }
#pragma unroll
        for (int mt = 0; mt < 4; mt++) {
#pragma unroll
            for (int r = 0; r < 4; r++) {
                int lrow = wr * 64 + mt * 16 + quad * 4 + r;
                int e = bm * 128 + lrow;
                int ec = e < M ? e : M - 1;
                int s = srcp[ec], d = dstp[ec];
                const float* hsr = Hs + (size_t)s * 256;
                const float* hdr = Hd + (size_t)d * 256;
                float part = 0.f;
#pragma unroll
                for (int nt = 0; nt < 8; nt++) {
                    int col = wc * 128 + nt * 16 + col_l;
                    part += fmaxf(acc[mt][nt][r] + hsr[col] + hdr[col] + b1c[nt], 0.f)
                            * w2c[nt];
                }
#pragma unroll
                for (int m = 8; m > 0; m >>= 1) part += __shfl_xor(part, m, 64);
                if (col_l == 0) atomicAdd(&red[lrow], part);
            }
        }
        __syncthreads();
        if (tid < 128) {
            int e = bm * 128 + tid;
            if (e < M) {
                float logit = red[tid] + b2v[0];
                ((float*)out)[e] = logit;
                unsigned y0, y1;
                threefry2x32(0u, 42u, 0u, (unsigned)e, y0, y1);
                unsigned bits = y0 ^ y1;
                float f = __uint_as_float((bits >> 9) | 0x3F800000u) - 1.0f;
                float u = fmaxf(1e-10f, f + 1e-10f);
                float noise = logf(u) - logf(1.0f - u);
                out_s[e] = 1.0f / (1.0f + expf(-(logit + noise)));
            }
        }
        return;
    }

    float bs[8];
    if (EPI >= 2) {
#pragma unroll
        for (int nt = 0; nt < 8; nt++) bs[nt] = bias[wc * 128 + nt * 16 + col_l];
    }
#pragma unroll
    for (int mt = 0; mt < 4; mt++) {
#pragma unroll
        for (int nt = 0; nt < 8; nt++) {
            int colg = wc * 128 + nt * 16 + col_l;
#pragma unroll
            for (int r = 0; r < 4; r++) {
                int rg = bm * 128 + wr * 64 + mt * 16 + quad * 4 + r;
                if (rg < M) {
                    float v = acc[mt][nt][r];
                    if (EPI >= 2) v += bs[nt];
                    if (EPI == 3) v = fmaxf(v, 0.f);
                    if (EPI == 0)
                        ((float*)Osel)[(size_t)rg * rsOut + colg] = v;
                    else
                        ((ushort_t*)Osel)[(size_t)rg * rsOut + colg] = f2bf(v);
                }
            }
        }
    }
}

// ---------------------------------------------------------------------------
// Mean aggregation over bf16 features. One wave per node; lane owns 4 cols.
// ---------------------------------------------------------------------------
__global__ __launch_bounds__(64) void agg_bf_kernel(
        const ushort_t* __restrict__ xin, int rsx,
        const ushort_t* __restrict__ eaf, const ushort_t* __restrict__ ear,
        const int* __restrict__ src, const int* __restrict__ dst,
        const int* __restrict__ row_start, const int* __restrict__ elist,
        const int* __restrict__ deg, ushort_t* __restrict__ agg) {
    int n = blockIdx.x;
    int c = threadIdx.x * 4;
    float ax = 0.f, ay = 0.f, az = 0.f, aw = 0.f;
    int beg = row_start[n], end = row_start[n + 1];
    for (int p = beg; p < end; p++) {
        int i = elist[p];
        const ushort_t* xr;
        const ushort_t* er;
        if (i < NE) { xr = xin + (size_t)src[i] * rsx; er = eaf + (size_t)i * 256; }
        else { int j = i - NE; xr = xin + (size_t)dst[j] * rsx; er = ear + (size_t)j * 256; }
        ushort4 xv = *(const ushort4*)(xr + c);
        ushort4 ev = *(const ushort4*)(er + c);
        ax += bf2f(xv.x) + bf2f(ev.x);
        ay += bf2f(xv.y) + bf2f(ev.y);
        az += bf2f(xv.z) + bf2f(ev.z);
        aw += bf2f(xv.w) + bf2f(ev.w);
    }
    float d = fmaxf((float)deg[n], 1.0f);
    ushort4 o;
    o.x = f2bf(ax / d); o.y = f2bf(ay / d); o.z = f2bf(az / d); o.w = f2bf(aw / d);
    *(ushort4*)(agg + (size_t)n * 256 + c) = o;
}

// ---------------------------------------------------------------------------
extern "C" void kernel_launch(void* const* d_in, const int* in_sizes, int n_in,
                              void* d_out, int out_size, void* d_ws, size_t ws_size,
                              hipStream_t stream) {
    const float* x        = (const float*)d_in[0];
    const float* ea       = (const float*)d_in[1];
    const float* qemb     = (const float*)d_in[2];
    const int*   eidx     = (const int*)d_in[3];
    const float* W_rev1   = (const float*)d_in[4];
    const float* b_rev1   = (const float*)d_in[5];
    const float* W_rev2   = (const float*)d_in[6];
    const float* b_rev2   = (const float*)d_in[7];
    const float* W_sage1  = (const float*)d_in[8];
    const float* b_sage1  = (const float*)d_in[9];
    const float* W_sage2  = (const float*)d_in[10];
    const float* b_sage2  = (const float*)d_in[11];
    const float* W_pred1  = (const float*)d_in[12];
    const float* b_pred1  = (const float*)d_in[13];
    const float* W_pred2  = (const float*)d_in[14];
    const float* b_pred2  = (const float*)d_in[15];
    float* out = (float*)d_out;

    const int* src = eidx;
    const int* dst = eidx + NE;

    // ---- workspace layout ----
    char* w = (char*)d_ws;
    ushort_t* ea_bf  = (ushort_t*)w; w += (size_t)NE * 256 * 2;   // 102.4 MB
    ushort_t* hid_bf = (ushort_t*)w; w += (size_t)NE * 256 * 2;   // 102.4 MB
    ushort_t* ea_rev_bf = (ushort_t*)w; w += (size_t)NE * 256 * 2;// 102.4 MB
    ushort_t* x_bf   = (ushort_t*)w; w += (size_t)NN * 256 * 2;
    ushort_t* H      = (ushort_t*)w; w += (size_t)NN * 512 * 2;   // [h1|h2]
    ushort_t* agg_bf = (ushort_t*)w; w += (size_t)NN * 256 * 2;
    float*    Hsrc   = (float*)w;    w += (size_t)NN * 256 * 4;
    float*    Hdst   = (float*)w;    w += (size_t)NN * 256 * 4;
    ushort_t* Wt_rev1  = (ushort_t*)w; w += 256 * 256 * 2;
    ushort_t* Wt_rev2  = (ushort_t*)w; w += 256 * 256 * 2;
    ushort_t* Wt_sage1 = (ushort_t*)w; w += 256 * 512 * 2;
    ushort_t* Wt_sage2 = (ushort_t*)w; w += 256 * 512 * 2;
    ushort_t* Wt_src   = (ushort_t*)w; w += 256 * 512 * 2;
    ushort_t* Wt_dst   = (ushort_t*)w; w += 256 * 512 * 2;
    ushort_t* Wt_edge  = (ushort_t*)w; w += 256 * 512 * 2;
    int* deg       = (int*)w; w += (size_t)NN * 4;
    int* row_start = (int*)w; w += (size_t)(NN + 1) * 4;
    int* cursor    = (int*)w; w += (size_t)NN * 4;
    int* elist     = (int*)w; w += (size_t)NE2 * 4;

    const int EB = (NE + 127) / 128;   // 1563
    const int NB = (NN + 127) / 128;   // 157

    // ---- CSR ----
    hipMemsetAsync(deg, 0, (size_t)NN * 4, stream);
    deg_kernel<<<(NE2 + 255) / 256, 256, 0, stream>>>(src, dst, deg);
    prefix_kernel<<<1, 1024, 0, stream>>>(deg, row_start, cursor);
    scatter_kernel<<<(NE2 + 255) / 256, 256, 0, stream>>>(src, dst, cursor, elist);

    // ---- all weight transposes, one launch ----
    TA ta;
    ta.d[0] = { W_rev1,  Wt_rev1,  256, 0,   256 };
    ta.d[1] = { W_rev2,  Wt_rev2,  256, 0,   256 };
    ta.d[2] = { W_sage1, Wt_sage1, 512, 0,   512 };
    ta.d[3] = { W_sage2, Wt_sage2, 512, 0,   512 };
    ta.d[4] = { W_pred1 + (size_t)256 * 256,  Wt_src,  512, 0,   512 };
    ta.d[5] = { W_pred1 + (size_t)1024 * 256, Wt_dst,  512, 0,   512 };
    ta.d[6] = { W_pred1,                      Wt_edge, 512, 0,   256 };
    ta.d[7] = { W_pred1 + (size_t)768 * 256,  Wt_edge, 512, 256, 256 };
    transpose_all_kernel<<<dim3(512, 8), 256, 0, stream>>>(ta);

    // ---- activations to bf16 (ea + x, one launch) ----
    conv2_kernel<<<((NE + NN) * 32 + 255) / 256, 256, 0, stream>>>(
        ea, ea_bf, NE * 32, x, x_bf, NN * 32);

    // ---- reverse-edge MLP ----
    mfma_gemm<256, 3, false><<<EB, 256, 0, stream>>>(
        ea_bf, 256, nullptr, 0, Wt_rev1, nullptr, b_rev1,
        hid_bf, nullptr, 256, NE, nullptr, nullptr, nullptr, nullptr, nullptr, nullptr, nullptr);
    mfma_gemm<256, 2, false><<<EB, 256, 0, stream>>>(
        hid_bf, 256, nullptr, 0, Wt_rev2, nullptr, b_rev2,
        ea_rev_bf, nullptr, 256, NE, nullptr, nullptr, nullptr, nullptr, nullptr, nullptr, nullptr);

    // ---- SAGE layer 1 ----
    agg_bf_kernel<<<NN, 64, 0, stream>>>(x_bf, 256, ea_bf, ea_rev_bf,
                                         src, dst, row_start, elist, deg, agg_bf);
    mfma_gemm<512, 3, false><<<NB, 256, 0, stream>>>(
        x_bf, 256, agg_bf, 256, Wt_sage1, nullptr, b_sage1,
        H, nullptr, 512, NN, nullptr, nullptr, nullptr, nullptr, nullptr, nullptr, nullptr);

    // ---- SAGE layer 2 ----
    agg_bf_kernel<<<NN, 64, 0, stream>>>(H, 512, ea_bf, ea_rev_bf,
                                         src, dst, row_start, elist, deg, agg_bf);
    mfma_gemm<512, 3, false><<<NB, 256, 0, stream>>>(
        H, 512, agg_bf, 256, Wt_sage2, nullptr, b_sage2,
        H + 256, nullptr, 512, NN, nullptr, nullptr, nullptr, nullptr, nullptr, nullptr, nullptr);

    // ---- node-side pred contributions: Hsrc & Hdst in one paired launch ----
    mfma_gemm<512, 0, false><<<dim3(NB, 2), 256, 0, stream>>>(
        H, 512, H + 256, 512, Wt_src, Wt_dst, nullptr,
        Hsrc, Hdst, 256, NN, nullptr, nullptr, nullptr, nullptr, nullptr, nullptr, nullptr);

    // ---- edge GEMM + fused pred head (q read as fp32, converted in staging) ----
    mfma_gemm<512, 4, true><<<EB, 256, 0, stream>>>(
        qemb, 256, ea_bf, 256, Wt_edge, nullptr, b_pred1,
        out, nullptr, 0, NE, src, dst, Hsrc, Hdst, W_pred2, b_pred2, out + NE);
}